// Round 9
// baseline (1567.928 us; speedup 1.0000x reference)
//
#include <hip/hip_runtime.h>
#include <hip/hip_bf16.h>
#include <math.h>

#define N_NODES 100000
#define NE      3200000
#define TWO_NE  (2 * NE)
#define TWO_N   (2 * N_NODES)
#define H       32
#define DAMPING 0.1f
#define LN_EPS  1e-5f

#define NBUCK    782           // ceil(2N / 256) coarse dst buckets (256 rows each)
#define CAP      8704          // bucket capacity (mean 8192 + 5.7 sigma)
#define EPB      8192          // edges per scatter block
#define NBLK_A   ((TWO_NE + EPB - 1) / EPB)   // 782
#define GSTRIDE  16            // gcur padding: one cursor per 64B line

// ---------------------------------------------------------------------------
// Kernel 0: init per-bucket cursors (line-padded).
// ---------------------------------------------------------------------------
__global__ __launch_bounds__(256) void init_kernel(int* __restrict__ gcur)
{
    int i = blockIdx.x * 256 + threadIdx.x;
    if (i < NBUCK) gcur[i * GSTRIDE] = i * CAP;
}

// ---------------------------------------------------------------------------
// Kernel 1 (pass A): LDS counting-sort edges by coarse bucket; one global
// claim per (block,bucket); coalesced run writes.
// rec = (dst' & 255) << 18 | src'   (src' < 2^18)
// ---------------------------------------------------------------------------
__global__ __launch_bounds__(256) void bucket_scatter_kernel(
    const int* __restrict__ ep, const int* __restrict__ en,
    int* __restrict__ gcur, unsigned int* __restrict__ buf)
{
    __shared__ int hist[NBUCK];
    __shared__ int lexcl[NBUCK];
    __shared__ int lcur[NBUCK];
    __shared__ int claim[NBUCK];
    __shared__ int partial[256];
    __shared__ unsigned int srec[EPB];
    __shared__ unsigned short sbid[EPB];

    int t = threadIdx.x;
    for (int i = t; i < NBUCK; i += 256) { hist[i] = 0; lcur[i] = 0; }
    __syncthreads();

    int base = blockIdx.x * EPB;
    unsigned int regR[EPB / 256];
    short regB[EPB / 256];
    #pragma unroll
    for (int j = 0; j < EPB / 1024; j++) {
        int i = base + (j * 256 + t) * 4;   // 4-aligned; never straddles NE
        if (i < TWO_NE) {
            int g = i >= NE;
            int e = i - g * NE;
            const int* eix = g ? en : ep;
            int4 s4 = *(const int4*)(eix + e);
            int4 d4 = *(const int4*)(eix + NE + e);
            int off = g * N_NODES;
            int ss[4] = {s4.x, s4.y, s4.z, s4.w};
            int dd[4] = {d4.x, d4.y, d4.z, d4.w};
            #pragma unroll
            for (int k = 0; k < 4; k++) {
                int src = ss[k] + off;
                int dst = dd[k] + off;
                int b = dst >> 8;
                regB[j * 4 + k] = (short)b;
                regR[j * 4 + k] = ((unsigned int)(dst & 255) << 18) | (unsigned int)src;
                atomicAdd(&hist[b], 1);
            }
        } else {
            #pragma unroll
            for (int k = 0; k < 4; k++) regB[j * 4 + k] = -1;
        }
    }
    __syncthreads();

    // exclusive scan over hist[0..NBUCK): 4 cells/thread + Hillis over partials
    int h0[4]; int ssum = 0;
    #pragma unroll
    for (int k = 0; k < 4; k++) {
        int idx = t * 4 + k;
        h0[k] = (idx < NBUCK) ? hist[idx] : 0;
        ssum += h0[k];
    }
    partial[t] = ssum;
    __syncthreads();
    for (int off = 1; off < 256; off <<= 1) {
        int u = (t >= off) ? partial[t - off] : 0;
        __syncthreads();
        partial[t] += u;
        __syncthreads();
    }
    int run = partial[t] - ssum;
    #pragma unroll
    for (int k = 0; k < 4; k++) {
        int idx = t * 4 + k;
        if (idx < NBUCK) lexcl[idx] = run;
        run += h0[k];
    }
    __syncthreads();

    // claim contiguous global space per nonempty bucket
    for (int b = t; b < NBUCK; b += 256) {
        int c = hist[b];
        claim[b] = c ? atomicAdd(&gcur[b * GSTRIDE], c) : 0;
    }
    __syncthreads();

    // place edges sorted-by-bucket into LDS
    #pragma unroll
    for (int j = 0; j < EPB / 256; j++) {
        int b = regB[j];
        if (b >= 0) {
            int r = atomicAdd(&lcur[b], 1);
            int s = lexcl[b] + r;
            srec[s] = regR[j];
            sbid[s] = (unsigned short)b;
        }
    }
    __syncthreads();

    // coalesced-run writes: consecutive s within a bucket -> consecutive global
    int cnt = partial[255];
    for (int s = t; s < cnt; s += 256) {
        int b = sbid[s];
        buf[claim[b] + (s - lexcl[b])] = srec[s];
    }
}

// ---------------------------------------------------------------------------
// Kernel 2: per-bucket degree histogram -> inv (needed by ln_xw pre-scale).
// ---------------------------------------------------------------------------
__global__ __launch_bounds__(256) void degree_kernel(
    const int* __restrict__ gcur,
    const unsigned int* __restrict__ buf,
    float* __restrict__ inv)
{
    __shared__ int hist[256];
    int t = threadIdx.x;
    int b = blockIdx.x;
    int gbase = b * CAP;
    int cnt = gcur[b * GSTRIDE] - gbase;
    if (cnt > CAP) cnt = CAP;
    hist[t] = 0;
    __syncthreads();
    for (int i = t; i < cnt; i += 256)
        atomicAdd(&hist[buf[gbase + i] >> 18], 1);
    __syncthreads();
    int row = (b << 8) + t;
    if (row < TWO_N) inv[row] = rsqrtf((float)hist[t] + 1.0f);
}

// ---------------------------------------------------------------------------
// Kernel 3: LayerNorm + two HxH GEMVs, outputs pre-scaled by inv[row],
// packed to bf16 pairs: xh[row][fp] = {feat 2fp, feat 2fp+1}, row' in [0,2N).
// ---------------------------------------------------------------------------
__global__ __launch_bounds__(256) void ln_xw_kernel(
    const float* __restrict__ h,
    const float* __restrict__ gamma,
    const float* __restrict__ beta,
    const float* __restrict__ Wp,
    const float* __restrict__ Wn,
    const float* __restrict__ inv,
    __hip_bfloat162* __restrict__ xh)
{
    __shared__ float sWp[H * H];
    __shared__ float sWn[H * H];
    __shared__ float sHn[8][H];

    int tid = threadIdx.x;
    for (int i = tid; i < H * H; i += 256) { sWp[i] = Wp[i]; sWn[i] = Wn[i]; }

    int lane = tid & 31;
    int r    = tid >> 5;
    int row  = blockIdx.x * 8 + r;

    float x = h[row * H + lane];
    float s = x;
    #pragma unroll
    for (int m = 16; m >= 1; m >>= 1) s += __shfl_xor(s, m);
    float mu = s * (1.0f / 32.0f);
    float d  = x - mu;
    float v  = d * d;
    #pragma unroll
    for (int m = 16; m >= 1; m >>= 1) v += __shfl_xor(v, m);
    float rstd = rsqrtf(v * (1.0f / 32.0f) + LN_EPS);
    float hn   = d * rstd * gamma[lane] + beta[lane];

    sHn[r][lane] = hn;
    __syncthreads();

    float accp = 0.f, accn = 0.f;
    #pragma unroll
    for (int k = 0; k < H; k++) {
        float hk = sHn[r][k];
        accp += hk * sWp[k * H + lane];
        accn += hk * sWn[k * H + lane];
    }
    float vp = accp * inv[row];
    float vn = accn * inv[N_NODES + row];

    // pack feature pairs: even lane stores {self, odd-partner}
    float vp_nb = __shfl_xor(vp, 1);
    float vn_nb = __shfl_xor(vn, 1);
    if ((lane & 1) == 0) {
        __hip_bfloat162 pv, nv;
        pv.x = __float2bfloat16(vp); pv.y = __float2bfloat16(vp_nb);
        nv.x = __float2bfloat16(vn); nv.y = __float2bfloat16(vn_nb);
        int fp = lane >> 1;
        xh[row * 16 + fp]               = pv;
        xh[(N_NODES + row) * 16 + fp]   = nv;
    }
}

// ---------------------------------------------------------------------------
// Kernel 4: streaming LDS-accumulate per bucket. acc[256][32] fp32 in LDS,
// initialized with the self-loop term. Wave = 4 quarters x 16 fp lanes; each
// quarter handles 4 records per iteration (4-deep MLP). Conflict pattern:
// feature index == LDS bank -> conflict-free per quarter, ~4-way across wave.
// ---------------------------------------------------------------------------
__global__ __launch_bounds__(256) void accum_kernel(
    const int* __restrict__ gcur,
    const unsigned int* __restrict__ buf,
    const __hip_bfloat16* __restrict__ xhb,    // flat bf16 view [2N][32]
    const __hip_bfloat162* __restrict__ xh,    // pair view [2N][16]
    __hip_bfloat16* __restrict__ hp)
{
    __shared__ float acc[256 * 32];

    int t = threadIdx.x;
    int b = blockIdx.x;
    int gbase = b * CAP;
    int cnt = gcur[b * GSTRIDE] - gbase;
    if (cnt > CAP) cnt = CAP;

    int rowbase = b << 8;
    for (int i = t; i < 8192; i += 256) {
        int row = rowbase + (i >> 5);
        acc[i] = (row < TWO_N) ? __bfloat162float(xhb[row * 32 + (i & 31)]) : 0.f;
    }
    __syncthreads();

    int wave = t >> 6, lane = t & 63, grp = lane >> 4, fp = lane & 15;
    int fp2 = fp * 2;

    for (int j = wave * 16; j < cnt; j += 64) {
        int i0 = j + grp * 4;
        bool d0 = i0 + 0 < cnt, d1 = i0 + 1 < cnt, d2 = i0 + 2 < cnt, d3 = i0 + 3 < cnt;
        unsigned int r0 = d0 ? buf[gbase + i0 + 0] : 0;
        unsigned int r1 = d1 ? buf[gbase + i0 + 1] : 0;
        unsigned int r2 = d2 ? buf[gbase + i0 + 2] : 0;
        unsigned int r3 = d3 ? buf[gbase + i0 + 3] : 0;
        __hip_bfloat162 v0, v1, v2, v3;
        if (d0) v0 = xh[(r0 & 0x3FFFFu) * 16 + fp];
        if (d1) v1 = xh[(r1 & 0x3FFFFu) * 16 + fp];
        if (d2) v2 = xh[(r2 & 0x3FFFFu) * 16 + fp];
        if (d3) v3 = xh[(r3 & 0x3FFFFu) * 16 + fp];
        if (d0) {
            int a = (int)(r0 >> 18) * 32 + fp2;
            atomicAdd(&acc[a],     __bfloat162float(v0.x));
            atomicAdd(&acc[a + 1], __bfloat162float(v0.y));
        }
        if (d1) {
            int a = (int)(r1 >> 18) * 32 + fp2;
            atomicAdd(&acc[a],     __bfloat162float(v1.x));
            atomicAdd(&acc[a + 1], __bfloat162float(v1.y));
        }
        if (d2) {
            int a = (int)(r2 >> 18) * 32 + fp2;
            atomicAdd(&acc[a],     __bfloat162float(v2.x));
            atomicAdd(&acc[a + 1], __bfloat162float(v2.y));
        }
        if (d3) {
            int a = (int)(r3 >> 18) * 32 + fp2;
            atomicAdd(&acc[a],     __bfloat162float(v3.x));
            atomicAdd(&acc[a + 1], __bfloat162float(v3.y));
        }
    }
    __syncthreads();

    for (int i = t; i < 8192; i += 256) {
        int row = rowbase + (i >> 5);
        if (row < TWO_N) hp[row * 32 + (i & 31)] = __float2bfloat16(acc[i]);
    }
}

// ---------------------------------------------------------------------------
// Kernel 5: epilogue — inv post-scale + bias + LN recompute + psi GEMV +
// tanh + damping + clip. 8 rows x 32 lanes per block.
// ---------------------------------------------------------------------------
__global__ __launch_bounds__(256) void epilogue_kernel(
    const float* __restrict__ h,
    const float* __restrict__ gamma,
    const float* __restrict__ beta,
    const __hip_bfloat16* __restrict__ hp,
    const float* __restrict__ inv,
    const float* __restrict__ bp,
    const float* __restrict__ bn,
    const float* __restrict__ Wpsi,
    float* __restrict__ out)
{
    __shared__ float sW[2 * H * H];
    __shared__ float sP[8][H];
    __shared__ float sM[8][H];

    int tid = threadIdx.x;
    for (int i = tid; i < 2 * H * H; i += 256) sW[i] = Wpsi[i];

    int lane = tid & 31;
    int r    = tid >> 5;
    int row  = blockIdx.x * 8 + r;
    int rn   = N_NODES + row;

    float hpv = inv[row] * __bfloat162float(hp[row * 32 + lane]) + bp[lane];
    float hmv = inv[rn]  * __bfloat162float(hp[rn  * 32 + lane]) + bn[lane];
    sP[r][lane] = hpv;
    sM[r][lane] = hmv;

    // layernorm recompute for damping term
    float x = h[row * H + lane];
    float s = x;
    #pragma unroll
    for (int m = 16; m >= 1; m >>= 1) s += __shfl_xor(s, m);
    float mu = s * (1.0f / 32.0f);
    float d  = x - mu;
    float v  = d * d;
    #pragma unroll
    for (int m = 16; m >= 1; m >>= 1) v += __shfl_xor(v, m);
    float rstd = rsqrtf(v * (1.0f / 32.0f) + LN_EPS);
    float hn   = d * rstd * gamma[lane] + beta[lane];

    __syncthreads();

    float acc = 0.f;
    #pragma unroll
    for (int k = 0; k < H; k++) {
        acc += sP[r][k] * sW[k * H + lane];
        acc += sM[r][k] * sW[(H + k) * H + lane];
    }

    float delta = tanhf(acc) - DAMPING * hn;
    delta = fminf(fmaxf(delta, -50.f), 50.f);
    out[row * H + lane] = delta;
}

// ---------------------------------------------------------------------------
extern "C" void kernel_launch(void* const* d_in, const int* in_sizes, int n_in,
                              void* d_out, int out_size, void* d_ws, size_t ws_size,
                              hipStream_t stream)
{
    const float* h      = (const float*)d_in[1];
    const int*   ep     = (const int*)  d_in[2];   // (2, E)
    const int*   en     = (const int*)  d_in[3];
    const float* gamma  = (const float*)d_in[4];
    const float* beta   = (const float*)d_in[5];
    const float* Wp     = (const float*)d_in[6];
    const float* bp     = (const float*)d_in[7];
    const float* Wn     = (const float*)d_in[8];
    const float* bn     = (const float*)d_in[9];
    const float* Wpsi   = (const float*)d_in[10];
    float* out = (float*)d_out;

    // workspace layout (~53.7 MB):
    unsigned int* buf = (unsigned int*)d_ws;                     // NBUCK*CAP u32 (27.2 MB)
    __hip_bfloat162* xh = (__hip_bfloat162*)(buf + (size_t)NBUCK * CAP); // 2N*16 (12.8 MB)
    __hip_bfloat16* hp = (__hip_bfloat16*)(xh + (size_t)TWO_N * 16);     // 2N*32 (12.8 MB)
    float* inv  = (float*)(hp + (size_t)TWO_N * 32);             // 2N f32 (0.8 MB)
    int*   gcur = (int*)(inv + TWO_N);                           // NBUCK*16 (50 KB)

    const __hip_bfloat16* xhb = (const __hip_bfloat16*)xh;       // flat bf16 view

    init_kernel<<<4, 256, 0, stream>>>(gcur);

    bucket_scatter_kernel<<<NBLK_A, 256, 0, stream>>>(ep, en, gcur, buf);

    degree_kernel<<<NBUCK, 256, 0, stream>>>(gcur, buf, inv);

    ln_xw_kernel<<<N_NODES / 8, 256, 0, stream>>>(h, gamma, beta, Wp, Wn, inv, xh);

    accum_kernel<<<NBUCK, 256, 0, stream>>>(gcur, buf, xhb, xh, hp);

    epilogue_kernel<<<N_NODES / 8, 256, 0, stream>>>(
        h, gamma, beta, hp, inv, bp, bn, Wpsi, out);
}

// Round 10
// 462.986 us; speedup vs baseline: 3.3866x; 3.3866x over previous
//
#include <hip/hip_runtime.h>
#include <hip/hip_bf16.h>
#include <math.h>

#define N_NODES 100000
#define NE      3200000
#define TWO_NE  (2 * NE)
#define TWO_N   (2 * N_NODES)
#define H       32
#define DAMPING 0.1f
#define LN_EPS  1e-5f

#define NBUCK    782           // ceil(2N / 256) coarse dst buckets (256 rows each)
#define CAP      8704          // bucket capacity (mean 8192 + 5.7 sigma)
#define EPB      8192          // edges per scatter block
#define NBLK_A   ((TWO_NE + EPB - 1) / EPB)   // 782
#define GSTRIDE  16            // gcur padding: one cursor per 64B line
#define FXS      262144.0f     // fixed-point scale 2^18
#define FXSI     (1.0f / 262144.0f)

// ---------------------------------------------------------------------------
// Kernel 0: init per-bucket cursors (line-padded).
// ---------------------------------------------------------------------------
__global__ __launch_bounds__(256) void init_kernel(int* __restrict__ gcur)
{
    int i = blockIdx.x * 256 + threadIdx.x;
    if (i < NBUCK) gcur[i * GSTRIDE] = i * CAP;
}

// ---------------------------------------------------------------------------
// Kernel 1 (pass A): LDS counting-sort edges by coarse bucket; one global
// claim per (block,bucket); coalesced run writes.
// rec = (dst' & 255) << 18 | src'   (src' < 2^18)
// ---------------------------------------------------------------------------
__global__ __launch_bounds__(256) void bucket_scatter_kernel(
    const int* __restrict__ ep, const int* __restrict__ en,
    int* __restrict__ gcur, unsigned int* __restrict__ buf)
{
    __shared__ int hist[NBUCK];
    __shared__ int lexcl[NBUCK];
    __shared__ int lcur[NBUCK];
    __shared__ int claim[NBUCK];
    __shared__ int partial[256];
    __shared__ unsigned int srec[EPB];
    __shared__ unsigned short sbid[EPB];

    int t = threadIdx.x;
    for (int i = t; i < NBUCK; i += 256) { hist[i] = 0; lcur[i] = 0; }
    __syncthreads();

    int base = blockIdx.x * EPB;
    unsigned int regR[EPB / 256];
    short regB[EPB / 256];
    #pragma unroll
    for (int j = 0; j < EPB / 1024; j++) {
        int i = base + (j * 256 + t) * 4;   // 4-aligned; never straddles NE
        if (i < TWO_NE) {
            int g = i >= NE;
            int e = i - g * NE;
            const int* eix = g ? en : ep;
            int4 s4 = *(const int4*)(eix + e);
            int4 d4 = *(const int4*)(eix + NE + e);
            int off = g * N_NODES;
            int ss[4] = {s4.x, s4.y, s4.z, s4.w};
            int dd[4] = {d4.x, d4.y, d4.z, d4.w};
            #pragma unroll
            for (int k = 0; k < 4; k++) {
                int src = ss[k] + off;
                int dst = dd[k] + off;
                int b = dst >> 8;
                regB[j * 4 + k] = (short)b;
                regR[j * 4 + k] = ((unsigned int)(dst & 255) << 18) | (unsigned int)src;
                atomicAdd(&hist[b], 1);
            }
        } else {
            #pragma unroll
            for (int k = 0; k < 4; k++) regB[j * 4 + k] = -1;
        }
    }
    __syncthreads();

    // exclusive scan over hist[0..NBUCK): 4 cells/thread + Hillis over partials
    int h0[4]; int ssum = 0;
    #pragma unroll
    for (int k = 0; k < 4; k++) {
        int idx = t * 4 + k;
        h0[k] = (idx < NBUCK) ? hist[idx] : 0;
        ssum += h0[k];
    }
    partial[t] = ssum;
    __syncthreads();
    for (int off = 1; off < 256; off <<= 1) {
        int u = (t >= off) ? partial[t - off] : 0;
        __syncthreads();
        partial[t] += u;
        __syncthreads();
    }
    int run = partial[t] - ssum;
    #pragma unroll
    for (int k = 0; k < 4; k++) {
        int idx = t * 4 + k;
        if (idx < NBUCK) lexcl[idx] = run;
        run += h0[k];
    }
    __syncthreads();

    // claim contiguous global space per nonempty bucket
    for (int b = t; b < NBUCK; b += 256) {
        int c = hist[b];
        claim[b] = c ? atomicAdd(&gcur[b * GSTRIDE], c) : 0;
    }
    __syncthreads();

    // place edges sorted-by-bucket into LDS
    #pragma unroll
    for (int j = 0; j < EPB / 256; j++) {
        int b = regB[j];
        if (b >= 0) {
            int r = atomicAdd(&lcur[b], 1);
            int s = lexcl[b] + r;
            srec[s] = regR[j];
            sbid[s] = (unsigned short)b;
        }
    }
    __syncthreads();

    // coalesced-run writes: consecutive s within a bucket -> consecutive global
    int cnt = partial[255];
    for (int s = t; s < cnt; s += 256) {
        int b = sbid[s];
        buf[claim[b] + (s - lexcl[b])] = srec[s];
    }
}

// ---------------------------------------------------------------------------
// Kernel 2: per-bucket degree histogram -> inv (needed by ln_xw pre-scale).
// ---------------------------------------------------------------------------
__global__ __launch_bounds__(256) void degree_kernel(
    const int* __restrict__ gcur,
    const unsigned int* __restrict__ buf,
    float* __restrict__ inv)
{
    __shared__ int hist[256];
    int t = threadIdx.x;
    int b = blockIdx.x;
    int gbase = b * CAP;
    int cnt = gcur[b * GSTRIDE] - gbase;
    if (cnt > CAP) cnt = CAP;
    hist[t] = 0;
    __syncthreads();
    for (int i = t; i < cnt; i += 256)
        atomicAdd(&hist[buf[gbase + i] >> 18], 1);
    __syncthreads();
    int row = (b << 8) + t;
    if (row < TWO_N) inv[row] = rsqrtf((float)hist[t] + 1.0f);
}

// ---------------------------------------------------------------------------
// Kernel 3: LayerNorm + two HxH GEMVs, outputs pre-scaled by inv[row],
// packed to bf16 pairs: xh[row][fp] = {feat 2fp, feat 2fp+1}, row' in [0,2N).
// ---------------------------------------------------------------------------
__global__ __launch_bounds__(256) void ln_xw_kernel(
    const float* __restrict__ h,
    const float* __restrict__ gamma,
    const float* __restrict__ beta,
    const float* __restrict__ Wp,
    const float* __restrict__ Wn,
    const float* __restrict__ inv,
    __hip_bfloat162* __restrict__ xh)
{
    __shared__ float sWp[H * H];
    __shared__ float sWn[H * H];
    __shared__ float sHn[8][H];

    int tid = threadIdx.x;
    for (int i = tid; i < H * H; i += 256) { sWp[i] = Wp[i]; sWn[i] = Wn[i]; }

    int lane = tid & 31;
    int r    = tid >> 5;
    int row  = blockIdx.x * 8 + r;

    float x = h[row * H + lane];
    float s = x;
    #pragma unroll
    for (int m = 16; m >= 1; m >>= 1) s += __shfl_xor(s, m);
    float mu = s * (1.0f / 32.0f);
    float d  = x - mu;
    float v  = d * d;
    #pragma unroll
    for (int m = 16; m >= 1; m >>= 1) v += __shfl_xor(v, m);
    float rstd = rsqrtf(v * (1.0f / 32.0f) + LN_EPS);
    float hn   = d * rstd * gamma[lane] + beta[lane];

    sHn[r][lane] = hn;
    __syncthreads();

    float accp = 0.f, accn = 0.f;
    #pragma unroll
    for (int k = 0; k < H; k++) {
        float hk = sHn[r][k];
        accp += hk * sWp[k * H + lane];
        accn += hk * sWn[k * H + lane];
    }
    float vp = accp * inv[row];
    float vn = accn * inv[N_NODES + row];

    // pack feature pairs: even lane stores {self, odd-partner}
    float vp_nb = __shfl_xor(vp, 1);
    float vn_nb = __shfl_xor(vn, 1);
    if ((lane & 1) == 0) {
        __hip_bfloat162 pv, nv;
        pv.x = __float2bfloat16(vp); pv.y = __float2bfloat16(vp_nb);
        nv.x = __float2bfloat16(vn); nv.y = __float2bfloat16(vn_nb);
        int fp = lane >> 1;
        xh[row * 16 + fp]               = pv;
        xh[(N_NODES + row) * 16 + fp]   = nv;
    }
}

// ---------------------------------------------------------------------------
// Kernel 4: streaming LDS-accumulate per bucket, INT fixed-point (2^18).
// ds_add_u32 is native (unlike fp32 LDS atomicAdd, which lowered to a CAS
// loop and caused R9's 15x stall). Bank swizzle (f + 2*dst)&31 breaks the
// even-bank 4-way pattern. Wave = 4 quarters x 16 fp lanes, 4-deep MLP.
// ---------------------------------------------------------------------------
__global__ __launch_bounds__(256) void accum_kernel(
    const int* __restrict__ gcur,
    const unsigned int* __restrict__ buf,
    const __hip_bfloat162* __restrict__ xh,    // pair view [2N][16]
    __hip_bfloat16* __restrict__ hp)
{
    __shared__ int acc[256 * 32];

    int t = threadIdx.x;
    int b = blockIdx.x;
    int gbase = b * CAP;
    int cnt = gcur[b * GSTRIDE] - gbase;
    if (cnt > CAP) cnt = CAP;

    int rowbase = b << 8;

    // init with self-loop term (already inv-scaled), fixed-point, swizzled
    for (int i = t; i < 4096; i += 256) {
        int l  = i >> 4;                 // local row 0..255
        int fq = i & 15;                 // feature pair
        int row = rowbase + l;
        float vx = 0.f, vy = 0.f;
        if (row < TWO_N) {
            __hip_bfloat162 v = xh[row * 16 + fq];
            vx = __bfloat162float(v.x);
            vy = __bfloat162float(v.y);
        }
        int base32 = l * 32;
        acc[base32 + ((2 * fq     + 2 * l) & 31)] = __float2int_rn(vx * FXS);
        acc[base32 + ((2 * fq + 1 + 2 * l) & 31)] = __float2int_rn(vy * FXS);
    }
    __syncthreads();

    int wave = t >> 6, lane = t & 63, grp = lane >> 4, fq = lane & 15;
    int fp2 = fq * 2;

    for (int j = wave * 16; j < cnt; j += 64) {
        int i0 = j + grp * 4;
        bool d0 = i0 + 0 < cnt, d1 = i0 + 1 < cnt, d2 = i0 + 2 < cnt, d3 = i0 + 3 < cnt;
        unsigned int r0 = d0 ? buf[gbase + i0 + 0] : 0;
        unsigned int r1 = d1 ? buf[gbase + i0 + 1] : 0;
        unsigned int r2 = d2 ? buf[gbase + i0 + 2] : 0;
        unsigned int r3 = d3 ? buf[gbase + i0 + 3] : 0;
        __hip_bfloat162 v0, v1, v2, v3;
        if (d0) v0 = xh[(r0 & 0x3FFFFu) * 16 + fq];
        if (d1) v1 = xh[(r1 & 0x3FFFFu) * 16 + fq];
        if (d2) v2 = xh[(r2 & 0x3FFFFu) * 16 + fq];
        if (d3) v3 = xh[(r3 & 0x3FFFFu) * 16 + fq];
        if (d0) {
            int dl = (int)(r0 >> 18), b32 = dl * 32, rot = 2 * dl;
            atomicAdd(&acc[b32 + ((fp2     + rot) & 31)], __float2int_rn(__bfloat162float(v0.x) * FXS));
            atomicAdd(&acc[b32 + ((fp2 + 1 + rot) & 31)], __float2int_rn(__bfloat162float(v0.y) * FXS));
        }
        if (d1) {
            int dl = (int)(r1 >> 18), b32 = dl * 32, rot = 2 * dl;
            atomicAdd(&acc[b32 + ((fp2     + rot) & 31)], __float2int_rn(__bfloat162float(v1.x) * FXS));
            atomicAdd(&acc[b32 + ((fp2 + 1 + rot) & 31)], __float2int_rn(__bfloat162float(v1.y) * FXS));
        }
        if (d2) {
            int dl = (int)(r2 >> 18), b32 = dl * 32, rot = 2 * dl;
            atomicAdd(&acc[b32 + ((fp2     + rot) & 31)], __float2int_rn(__bfloat162float(v2.x) * FXS));
            atomicAdd(&acc[b32 + ((fp2 + 1 + rot) & 31)], __float2int_rn(__bfloat162float(v2.y) * FXS));
        }
        if (d3) {
            int dl = (int)(r3 >> 18), b32 = dl * 32, rot = 2 * dl;
            atomicAdd(&acc[b32 + ((fp2     + rot) & 31)], __float2int_rn(__bfloat162float(v3.x) * FXS));
            atomicAdd(&acc[b32 + ((fp2 + 1 + rot) & 31)], __float2int_rn(__bfloat162float(v3.y) * FXS));
        }
    }
    __syncthreads();

    // writeback: un-swizzle, scale back to float, store bf16
    for (int i = t; i < 8192; i += 256) {
        int l = i >> 5, f = i & 31;
        int row = rowbase + l;
        if (row < TWO_N) {
            int a = l * 32 + ((f + 2 * l) & 31);
            hp[row * 32 + f] = __float2bfloat16((float)acc[a] * FXSI);
        }
    }
}

// ---------------------------------------------------------------------------
// Kernel 5: epilogue — inv post-scale + bias + LN recompute + psi GEMV +
// tanh + damping + clip. 8 rows x 32 lanes per block.
// ---------------------------------------------------------------------------
__global__ __launch_bounds__(256) void epilogue_kernel(
    const float* __restrict__ h,
    const float* __restrict__ gamma,
    const float* __restrict__ beta,
    const __hip_bfloat16* __restrict__ hp,
    const float* __restrict__ inv,
    const float* __restrict__ bp,
    const float* __restrict__ bn,
    const float* __restrict__ Wpsi,
    float* __restrict__ out)
{
    __shared__ float sW[2 * H * H];
    __shared__ float sP[8][H];
    __shared__ float sM[8][H];

    int tid = threadIdx.x;
    for (int i = tid; i < 2 * H * H; i += 256) sW[i] = Wpsi[i];

    int lane = tid & 31;
    int r    = tid >> 5;
    int row  = blockIdx.x * 8 + r;
    int rn   = N_NODES + row;

    float hpv = inv[row] * __bfloat162float(hp[row * 32 + lane]) + bp[lane];
    float hmv = inv[rn]  * __bfloat162float(hp[rn  * 32 + lane]) + bn[lane];
    sP[r][lane] = hpv;
    sM[r][lane] = hmv;

    // layernorm recompute for damping term
    float x = h[row * H + lane];
    float s = x;
    #pragma unroll
    for (int m = 16; m >= 1; m >>= 1) s += __shfl_xor(s, m);
    float mu = s * (1.0f / 32.0f);
    float d  = x - mu;
    float v  = d * d;
    #pragma unroll
    for (int m = 16; m >= 1; m >>= 1) v += __shfl_xor(v, m);
    float rstd = rsqrtf(v * (1.0f / 32.0f) + LN_EPS);
    float hn   = d * rstd * gamma[lane] + beta[lane];

    __syncthreads();

    float acc = 0.f;
    #pragma unroll
    for (int k = 0; k < H; k++) {
        acc += sP[r][k] * sW[k * H + lane];
        acc += sM[r][k] * sW[(H + k) * H + lane];
    }

    float delta = tanhf(acc) - DAMPING * hn;
    delta = fminf(fmaxf(delta, -50.f), 50.f);
    out[row * H + lane] = delta;
}

// ---------------------------------------------------------------------------
extern "C" void kernel_launch(void* const* d_in, const int* in_sizes, int n_in,
                              void* d_out, int out_size, void* d_ws, size_t ws_size,
                              hipStream_t stream)
{
    const float* h      = (const float*)d_in[1];
    const int*   ep     = (const int*)  d_in[2];   // (2, E)
    const int*   en     = (const int*)  d_in[3];
    const float* gamma  = (const float*)d_in[4];
    const float* beta   = (const float*)d_in[5];
    const float* Wp     = (const float*)d_in[6];
    const float* bp     = (const float*)d_in[7];
    const float* Wn     = (const float*)d_in[8];
    const float* bn     = (const float*)d_in[9];
    const float* Wpsi   = (const float*)d_in[10];
    float* out = (float*)d_out;

    // workspace layout (~53.7 MB):
    unsigned int* buf = (unsigned int*)d_ws;                     // NBUCK*CAP u32 (27.2 MB)
    __hip_bfloat162* xh = (__hip_bfloat162*)(buf + (size_t)NBUCK * CAP); // 2N*16 (12.8 MB)
    __hip_bfloat16* hp = (__hip_bfloat16*)(xh + (size_t)TWO_N * 16);     // 2N*32 (12.8 MB)
    float* inv  = (float*)(hp + (size_t)TWO_N * 32);             // 2N f32 (0.8 MB)
    int*   gcur = (int*)(inv + TWO_N);                           // NBUCK*16 (50 KB)

    init_kernel<<<4, 256, 0, stream>>>(gcur);

    bucket_scatter_kernel<<<NBLK_A, 256, 0, stream>>>(ep, en, gcur, buf);

    degree_kernel<<<NBUCK, 256, 0, stream>>>(gcur, buf, inv);

    ln_xw_kernel<<<N_NODES / 8, 256, 0, stream>>>(h, gamma, beta, Wp, Wn, inv, xh);

    accum_kernel<<<NBUCK, 256, 0, stream>>>(gcur, buf, xh, hp);

    epilogue_kernel<<<N_NODES / 8, 256, 0, stream>>>(
        h, gamma, beta, hp, inv, bp, bn, Wpsi, out);
}